// Round 1
// baseline (4415.494 us; speedup 1.0000x reference)
//
#include <hip/hip_runtime.h>

#define N_NODES 100000
#define E_EDGES 1600000
#define D 64

// ---- GEMM: Wh = x @ W + b  (one thread per output element, W + x-rows in LDS)
__global__ void gemm_kernel(const float* __restrict__ x, const float* __restrict__ W,
                            const float* __restrict__ b, float* __restrict__ Wh, int n) {
    __shared__ float Wlds[D * D];
    __shared__ float xl[4 * D];
    int tid = threadIdx.x;
    #pragma unroll
    for (int i = tid; i < D * D; i += 256) Wlds[i] = W[i];
    int idx = blockIdx.x * 256 + tid;
    if (idx < n * D) xl[tid] = x[idx];
    __syncthreads();
    if (idx >= n * D) return;
    int r = tid >> 6, col = tid & 63;
    float acc = 0.f;
    #pragma unroll
    for (int k = 0; k < D; ++k) acc += xl[r * D + k] * Wlds[k * D + col];
    Wh[idx] = acc + b[col];
}

// ---- degree count (one int atomic per edge)
__global__ void degree_kernel(const int* __restrict__ dst, unsigned* __restrict__ deg, int nE) {
    int i = blockIdx.x * 256 + threadIdx.x;
    if (i < nE) atomicAdd(&deg[dst[i]], 1u);
}

// ---- deg -> 1/deg (0 if deg==0)
__global__ void inv_kernel(const unsigned* __restrict__ deg, float* __restrict__ inv, int n) {
    int i = blockIdx.x * 256 + threadIdx.x;
    if (i < n) {
        unsigned d = deg[i];
        inv[i] = d ? 1.0f / (float)d : 0.0f;
    }
}

// ---- scatter: out[dst] += Wh[src] * inv[dst]   (16 threads/edge, float4 gather)
__global__ void scatter_kernel(const float* __restrict__ Wh, const int* __restrict__ src,
                               const int* __restrict__ dst, const float* __restrict__ inv,
                               float* __restrict__ out, int nE) {
    int t = blockIdx.x * 256 + threadIdx.x;
    int e = t >> 4;
    if (e >= nE) return;
    int q = t & 15;
    int s = src[e], d = dst[e];
    float sc = inv[d];
    const float4 v = *reinterpret_cast<const float4*>(Wh + (size_t)s * D + q * 4);
    float* op = out + (size_t)d * D + q * 4;
    atomicAdd(op + 0, v.x * sc);
    atomicAdd(op + 1, v.y * sc);
    atomicAdd(op + 2, v.z * sc);
    atomicAdd(op + 3, v.w * sc);
}

extern "C" void kernel_launch(void* const* d_in, const int* in_sizes, int n_in,
                              void* d_out, int out_size, void* d_ws, size_t ws_size,
                              hipStream_t stream) {
    const float* x = (const float*)d_in[0];
    const float* W[3] = {(const float*)d_in[1], (const float*)d_in[5], (const float*)d_in[9]};
    const float* b[3] = {(const float*)d_in[2], (const float*)d_in[6], (const float*)d_in[10]};
    const int* src[3] = {(const int*)d_in[3], (const int*)d_in[7], (const int*)d_in[11]};
    const int* dst[3] = {(const int*)d_in[4], (const int*)d_in[8], (const int*)d_in[12]};
    float* out = (float*)d_out;

    char* ws = (char*)d_ws;
    float* Wh = (float*)ws;                                            // N*D floats
    unsigned* deg = (unsigned*)(ws + (size_t)N_NODES * D * 4);         // 3*N uints
    float* inv = (float*)(ws + (size_t)N_NODES * D * 4 + (size_t)3 * N_NODES * 4);  // 3*N floats

    hipMemsetAsync(d_out, 0, (size_t)N_NODES * D * 4, stream);
    hipMemsetAsync(deg, 0, (size_t)3 * N_NODES * 4, stream);

    for (int e = 0; e < 3; ++e)
        degree_kernel<<<(E_EDGES + 255) / 256, 256, 0, stream>>>(dst[e], deg + (size_t)e * N_NODES, E_EDGES);
    inv_kernel<<<(3 * N_NODES + 255) / 256, 256, 0, stream>>>(deg, inv, 3 * N_NODES);

    for (int e = 0; e < 3; ++e) {
        gemm_kernel<<<(N_NODES * D + 255) / 256, 256, 0, stream>>>(x, W[e], b[e], Wh, N_NODES);
        scatter_kernel<<<((long long)E_EDGES * 16 + 255) / 256, 256, 0, stream>>>(
            Wh, src[e], dst[e], inv + (size_t)e * N_NODES, out, E_EDGES);
    }
}

// Round 2
// 857.155 us; speedup vs baseline: 5.1513x; 5.1513x over previous
//
#include <hip/hip_runtime.h>

#define N_NODES 100000
#define E_EDGES 1600000
#define D 64
#define M3N (3 * N_NODES)
#define SCAN_BLOCKS ((M3N + 255) / 256)

// ---- GEMM: Wh = x @ W + b  (one thread per output element, W + x-rows in LDS)
__global__ void gemm_kernel(const float* __restrict__ x, const float* __restrict__ W,
                            const float* __restrict__ b, float* __restrict__ Wh, int n) {
    __shared__ float Wlds[D * D];
    __shared__ float xl[4 * D];
    int tid = threadIdx.x;
    #pragma unroll
    for (int i = tid; i < D * D; i += 256) Wlds[i] = W[i];
    int idx = blockIdx.x * 256 + tid;
    if (idx < n * D) xl[tid] = x[idx];
    __syncthreads();
    if (idx >= n * D) return;
    int r = tid >> 6, col = tid & 63;
    float acc = 0.f;
    #pragma unroll
    for (int k = 0; k < D; ++k) acc += xl[r * D + k] * Wlds[k * D + col];
    Wh[idx] = acc + b[col];
}

// ---- degree count (one int atomic per edge)
__global__ void degree_kernel(const int* __restrict__ dst, unsigned* __restrict__ deg, int nE) {
    int i = blockIdx.x * 256 + threadIdx.x;
    if (i < nE) atomicAdd(&deg[dst[i]], 1u);
}

// ---- scan step 1: per-block sums
__global__ void block_sum_kernel(const unsigned* __restrict__ deg, unsigned* __restrict__ bsum, int n) {
    __shared__ unsigned sm[256];
    int tid = threadIdx.x;
    int i = blockIdx.x * 256 + tid;
    sm[tid] = (i < n) ? deg[i] : 0u;
    __syncthreads();
    for (int s = 128; s > 0; s >>= 1) {
        if (tid < s) sm[tid] += sm[tid + s];
        __syncthreads();
    }
    if (tid == 0) bsum[blockIdx.x] = sm[0];
}

// ---- scan step 2: single-block exclusive scan of block sums
__global__ void scan_bsums_kernel(const unsigned* __restrict__ bsum, unsigned* __restrict__ boff, int nb) {
    __shared__ unsigned t[256];
    int tid = threadIdx.x;
    unsigned carry = 0;
    for (int base = 0; base < nb; base += 256) {
        unsigned v = (base + tid < nb) ? bsum[base + tid] : 0u;
        t[tid] = v;
        __syncthreads();
        for (int s = 1; s < 256; s <<= 1) {
            unsigned add = (tid >= s) ? t[tid - s] : 0u;
            __syncthreads();
            t[tid] += add;
            __syncthreads();
        }
        if (base + tid < nb) boff[base + tid] = carry + t[tid] - v;
        unsigned tot = t[255];
        __syncthreads();
        carry += tot;
    }
}

// ---- scan step 3: in-block exclusive scan + block offset
__global__ void block_scan_kernel(const unsigned* __restrict__ deg, const unsigned* __restrict__ boff,
                                  unsigned* __restrict__ off, int n) {
    __shared__ unsigned t[256];
    int tid = threadIdx.x;
    int i = blockIdx.x * 256 + tid;
    unsigned v = (i < n) ? deg[i] : 0u;
    t[tid] = v;
    __syncthreads();
    for (int s = 1; s < 256; s <<= 1) {
        unsigned add = (tid >= s) ? t[tid - s] : 0u;
        __syncthreads();
        t[tid] += add;
        __syncthreads();
    }
    if (i < n) off[i] = boff[blockIdx.x] + t[tid] - v;
}

// ---- CSR fill
__global__ void fill_csr_kernel(const int* __restrict__ src, const int* __restrict__ dst,
                                const unsigned* __restrict__ off, unsigned* __restrict__ cnt,
                                int* __restrict__ csr_src, int nE, int ebase) {
    int i = blockIdx.x * 256 + threadIdx.x;
    if (i >= nE) return;
    int d = dst[i];
    unsigned p = off[ebase + d] + atomicAdd(&cnt[ebase + d], 1u);
    csr_src[p] = src[i];
}

// ---- gather: one wave per node, lane = feature col
__global__ void gather_kernel(const float* __restrict__ Wh, const int* __restrict__ csr_src,
                              const unsigned* __restrict__ off, const unsigned* __restrict__ deg,
                              float* __restrict__ out, int ebase) {
    int wid = (blockIdx.x * 256 + threadIdx.x) >> 6;
    int lane = threadIdx.x & 63;
    if (wid >= N_NODES) return;
    unsigned cnt = __builtin_amdgcn_readfirstlane(deg[ebase + wid]);
    if (cnt == 0) return;
    unsigned start = __builtin_amdgcn_readfirstlane(off[ebase + wid]);
    const int* idx = csr_src + start;
    float a0 = 0.f, a1 = 0.f, a2 = 0.f, a3 = 0.f;
    unsigned j = 0;
    for (; j + 4 <= cnt; j += 4) {
        int s0 = idx[j], s1 = idx[j + 1], s2 = idx[j + 2], s3 = idx[j + 3];
        a0 += Wh[(size_t)s0 * D + lane];
        a1 += Wh[(size_t)s1 * D + lane];
        a2 += Wh[(size_t)s2 * D + lane];
        a3 += Wh[(size_t)s3 * D + lane];
    }
    for (; j < cnt; ++j) a0 += Wh[(size_t)idx[j] * D + lane];
    float sc = 1.0f / (float)cnt;
    out[(size_t)wid * D + lane] += ((a0 + a1) + (a2 + a3)) * sc;
}

extern "C" void kernel_launch(void* const* d_in, const int* in_sizes, int n_in,
                              void* d_out, int out_size, void* d_ws, size_t ws_size,
                              hipStream_t stream) {
    const float* x = (const float*)d_in[0];
    const float* W[3] = {(const float*)d_in[1], (const float*)d_in[5], (const float*)d_in[9]};
    const float* b[3] = {(const float*)d_in[2], (const float*)d_in[6], (const float*)d_in[10]};
    const int* src[3] = {(const int*)d_in[3], (const int*)d_in[7], (const int*)d_in[11]};
    const int* dst[3] = {(const int*)d_in[4], (const int*)d_in[8], (const int*)d_in[12]};
    float* out = (float*)d_out;

    char* ws = (char*)d_ws;
    size_t o = 0;
    float* Wh = (float*)(ws + o);         o += (size_t)N_NODES * D * 4;
    unsigned* deg = (unsigned*)(ws + o);  o += (size_t)M3N * 4;
    unsigned* off = (unsigned*)(ws + o);  o += (size_t)M3N * 4;
    unsigned* cnt = (unsigned*)(ws + o);  o += (size_t)M3N * 4;
    unsigned* bsum = (unsigned*)(ws + o); o += (size_t)((SCAN_BLOCKS + 1) & ~1) * 4;
    unsigned* boff = (unsigned*)(ws + o); o += (size_t)((SCAN_BLOCKS + 1) & ~1) * 4;
    int* csr_src = (int*)(ws + o);        o += (size_t)3 * E_EDGES * 4;

    hipMemsetAsync(out, 0, (size_t)N_NODES * D * 4, stream);
    hipMemsetAsync(deg, 0, (size_t)M3N * 4, stream);
    hipMemsetAsync(cnt, 0, (size_t)M3N * 4, stream);

    for (int e = 0; e < 3; ++e)
        degree_kernel<<<(E_EDGES + 255) / 256, 256, 0, stream>>>(dst[e], deg + (size_t)e * N_NODES, E_EDGES);

    block_sum_kernel<<<SCAN_BLOCKS, 256, 0, stream>>>(deg, bsum, M3N);
    scan_bsums_kernel<<<1, 256, 0, stream>>>(bsum, boff, SCAN_BLOCKS);
    block_scan_kernel<<<SCAN_BLOCKS, 256, 0, stream>>>(deg, boff, off, M3N);

    for (int e = 0; e < 3; ++e)
        fill_csr_kernel<<<(E_EDGES + 255) / 256, 256, 0, stream>>>(src[e], dst[e], off, cnt, csr_src,
                                                                   E_EDGES, e * N_NODES);

    for (int e = 0; e < 3; ++e) {
        gemm_kernel<<<(N_NODES * D + 255) / 256, 256, 0, stream>>>(x, W[e], b[e], Wh, N_NODES);
        gather_kernel<<<(N_NODES * 64 + 255) / 256, 256, 0, stream>>>(Wh, csr_src, off, deg, out, e * N_NODES);
    }
}